// Round 1
// baseline (273.504 us; speedup 1.0000x reference)
//
#include <hip/hip_runtime.h>
#include <hip/hip_bf16.h>

#define BB 4
#define NN 2048
#define CC 768
#define HH 12
#define DD 64
#define MTOT (BB*NN)   // 8192

typedef __attribute__((ext_vector_type(8))) short frag16;   // 8 bf16 (4 VGPR)
typedef __attribute__((ext_vector_type(4))) float f32x4;

static __device__ __forceinline__ float bf2f(unsigned short u) {
  unsigned int x = ((unsigned int)u) << 16;
  return __builtin_bit_cast(float, x);
}
static __device__ __forceinline__ unsigned short f2bf(float f) {
  __hip_bfloat16 h = __float2bfloat16(f);
  return __builtin_bit_cast(unsigned short, h);
}
static __device__ __forceinline__ void gload16(const void* g, void* l) {
  __builtin_amdgcn_global_load_lds((const __attribute__((address_space(1))) void*)g,
                                   (__attribute__((address_space(3))) void*)l, 16, 0, 0);
}

// ---------------- dtype detector: is the input buffer fp32 (1) or bf16 (0)? ----
__global__ void detect_k(const unsigned short* x, int* flag) {
  __shared__ int cnt;
  if (threadIdx.x == 0) cnt = 0;
  __syncthreads();
  float v = bf2f(x[threadIdx.x]);
  float a = fabsf(v);
  // fp32 data read as bf16: odd halves are mantissa bits -> wild exponents/NaN
  int weird = (!(a <= 1e4f)) || (a != 0.0f && a < 1e-10f);
  if (weird) atomicAdd(&cnt, 1);
  __syncthreads();
  if (threadIdx.x == 0) *flag = (cnt >= 24) ? 1 : 0;
}

// ---------------- convert input -> canonical bf16 bits ------------------------
__global__ void conv_k(const void* __restrict__ src, unsigned short* __restrict__ dst,
                       int n, const int* __restrict__ flag) {
  int fp32 = *flag;
  int i0 = (blockIdx.x * blockDim.x + threadIdx.x) * 4;
  int stride = gridDim.x * blockDim.x * 4;
  if (fp32) {
    const float* s = (const float*)src;
    for (int i = i0; i < n; i += stride) {
      float4 v = *reinterpret_cast<const float4*>(&s[i]);
      ushort4 o;
      o.x = f2bf(v.x); o.y = f2bf(v.y); o.z = f2bf(v.z); o.w = f2bf(v.w);
      *reinterpret_cast<ushort4*>(&dst[i]) = o;
    }
  } else {
    const unsigned short* s = (const unsigned short*)src;
    for (int i = i0; i < n; i += stride)
      *reinterpret_cast<ushort4*>(&dst[i]) = *reinterpret_cast<const ushort4*>(&s[i]);
  }
}

// ---------------- GEMM C = A * B^T (A[M,K] row-major, B[F,K] row-major) -------
// 128x128 tile, BK=32, 4 waves in 2x2, each wave 64x64 (4x4 of 16x16x32 mfma).
// EPI=0: scatter to qkv[3][B][H][N][D].  EPI=1: write out[M,CC] (dtype by flag).
template<int EPI>
__global__ __launch_bounds__(256) void gemm_bt(const unsigned short* __restrict__ A,
                                               const unsigned short* __restrict__ Bw,
                                               unsigned short* __restrict__ qkvbuf,
                                               void* __restrict__ outp,
                                               const int* __restrict__ flag) {
  constexpr int K = CC;
  __shared__ unsigned short Asm[128 * 32];
  __shared__ unsigned short Bsm[128 * 32];
  const int tid = threadIdx.x;
  const int lane = tid & 63;
  const int w = tid >> 6;
  const int wm = w >> 1, wn = w & 1;
  const int l15 = lane & 15;
  const int g = lane >> 4;
  const int m0 = blockIdx.x * 128;
  const int f0 = blockIdx.y * 128;

  f32x4 acc[4][4];
#pragma unroll
  for (int i = 0; i < 4; ++i)
#pragma unroll
    for (int j = 0; j < 4; ++j) acc[i][j] = (f32x4){0.f, 0.f, 0.f, 0.f};

  const unsigned short* Abase = A + (size_t)m0 * K;
  const unsigned short* Bbase = Bw + (size_t)f0 * K;

  for (int kt = 0; kt < K / 32; ++kt) {
    const int k0 = kt * 32;
    __syncthreads();   // protect LDS from previous iteration's readers
#pragma unroll
    for (int i = 0; i < 2; ++i) {
      int chunk = (i * 4 + w) * 64 + lane;   // 0..511
      int row = chunk >> 2;                  // 0..127
      int col = (chunk & 3) << 3;            // 0..24
      gload16(Abase + (size_t)row * K + k0 + col, (char*)Asm + (i * 4 + w) * 1024);
      gload16(Bbase + (size_t)row * K + k0 + col, (char*)Bsm + (i * 4 + w) * 1024);
    }
    __syncthreads();   // drains vmcnt (global_load_lds) + barrier

    frag16 af[4], bfv[4];
#pragma unroll
    for (int t = 0; t < 4; ++t) {
      af[t]  = *reinterpret_cast<const frag16*>(&Asm[(wm * 64 + t * 16 + l15) * 32 + 8 * g]);
      bfv[t] = *reinterpret_cast<const frag16*>(&Bsm[(wn * 64 + t * 16 + l15) * 32 + 8 * g]);
    }
#pragma unroll
    for (int i = 0; i < 4; ++i)
#pragma unroll
      for (int j = 0; j < 4; ++j)
        acc[i][j] = __builtin_amdgcn_mfma_f32_16x16x32_bf16(af[i], bfv[j], acc[i][j], 0, 0, 0);
  }

  // epilogue: D mapping (m89-verified): col = lane&15 (B-side), row = 4*(lane>>4)+r
  if constexpr (EPI == 0) {
#pragma unroll
    for (int i = 0; i < 4; ++i) {
      int mbase = m0 + wm * 64 + i * 16 + 4 * g;
#pragma unroll
      for (int j = 0; j < 4; ++j) {
        int f = f0 + wn * 64 + j * 16 + l15;
        int which = f / CC;
        int rem = f - which * CC;
        int h = rem >> 6, d = rem & 63;
#pragma unroll
        for (int r = 0; r < 4; ++r) {
          int mm = mbase + r;
          int b = mm >> 11, n = mm & 2047;
          size_t idx = ((((size_t)which * BB + b) * HH + h) * NN + n) * DD + d;
          qkvbuf[idx] = f2bf(acc[i][j][r]);
        }
      }
    }
  } else {
    int fp32 = *flag;
#pragma unroll
    for (int i = 0; i < 4; ++i) {
      int mbase = m0 + wm * 64 + i * 16 + 4 * g;
#pragma unroll
      for (int j = 0; j < 4; ++j) {
        int f = f0 + wn * 64 + j * 16 + l15;
#pragma unroll
        for (int r = 0; r < 4; ++r) {
          size_t idx = (size_t)(mbase + r) * CC + f;
          if (fp32) ((float*)outp)[idx] = acc[i][j][r];
          else ((unsigned short*)outp)[idx] = f2bf(acc[i][j][r]);
        }
      }
    }
  }
}

// ---------------- flash attention: 64 Q-rows/block, 4 waves x 16-row strips ---
__global__ __launch_bounds__(256) void attn_k(const unsigned short* __restrict__ qkv,
                                              unsigned short* __restrict__ ctx) {
  __shared__ unsigned short Klds[64 * 64];   // XOR-swizzled [kv][d]
  __shared__ unsigned short Vt[64 * 72];     // transposed [d][kv], stride 72
  __shared__ unsigned short Pl[64 * 72];     // per-wave 16-row strips, stride 72
  const int tid = threadIdx.x;
  const int lane = tid & 63;
  const int w = tid >> 6;
  const int l15 = lane & 15;
  const int g = lane >> 4;
  const int q0 = blockIdx.x * 64;
  const int bh = blockIdx.y;                 // b*H + h
  const size_t plane = (size_t)BB * HH * NN * DD;
  const unsigned short* Qg = qkv + (size_t)bh * NN * DD;
  const unsigned short* Kg = qkv + plane + (size_t)bh * NN * DD;
  const unsigned short* Vg = qkv + 2 * plane + (size_t)bh * NN * DD;

  // Q fragments for this wave's 16-row strip (A-operand; k-dim = d)
  frag16 aq[2];
  {
    int qrow = q0 + w * 16 + l15;
    aq[0] = *reinterpret_cast<const frag16*>(&Qg[(size_t)qrow * DD + 8 * g]);
    aq[1] = *reinterpret_cast<const frag16*>(&Qg[(size_t)qrow * DD + 32 + 8 * g]);
  }

  f32x4 acc[4];
#pragma unroll
  for (int t = 0; t < 4; ++t) acc[t] = (f32x4){0.f, 0.f, 0.f, 0.f};
  float mrun[4] = {-INFINITY, -INFINITY, -INFINITY, -INFINITY};
  float lrun[4] = {0.f, 0.f, 0.f, 0.f};

  unsigned short* Pw = Pl + w * 16 * 72;

  for (int kv = 0; kv < NN / 64; ++kv) {
    const int n0 = kv * 64;
    __syncthreads();
    // stage K (swizzled) and V^T: lane = kv-row, wave+iter pick d-chunk
#pragma unroll
    for (int i = 0; i < 2; ++i) {
      int d0 = 8 * w + 32 * i;
      uint4 kq = *reinterpret_cast<const uint4*>(&Kg[(size_t)(n0 + lane) * DD + d0]);
      *reinterpret_cast<uint4*>((char*)Klds + ((lane * 128 + d0 * 2) ^ ((lane & 7) << 4))) = kq;
      uint4 vq = *reinterpret_cast<const uint4*>(&Vg[(size_t)(n0 + lane) * DD + d0]);
      const unsigned short* vp = reinterpret_cast<const unsigned short*>(&vq);
#pragma unroll
      for (int j = 0; j < 8; ++j) Vt[(d0 + j) * 72 + lane] = vp[j];
    }
    __syncthreads();

    // S = Q K^T : D col = kv index, D row = q row
    f32x4 sc[4];
#pragma unroll
    for (int t = 0; t < 4; ++t) sc[t] = (f32x4){0.f, 0.f, 0.f, 0.f};
#pragma unroll
    for (int ks = 0; ks < 2; ++ks) {
#pragma unroll
      for (int t = 0; t < 4; ++t) {
        int krow = t * 16 + l15;
        frag16 kb = *reinterpret_cast<const frag16*>(
            (const char*)Klds + ((krow * 128 + ks * 64 + 16 * g) ^ ((krow & 7) << 4)));
        sc[t] = __builtin_amdgcn_mfma_f32_16x16x32_bf16(aq[ks], kb, sc[t], 0, 0, 0);
      }
    }
#pragma unroll
    for (int t = 0; t < 4; ++t) sc[t] *= 0.125f;   // 1/sqrt(64), exact in fp32

    // online softmax over 16-lane groups (cols of this row live in lanes l15)
    float mnew[4], corr[4], rs[4];
#pragma unroll
    for (int r = 0; r < 4; ++r) {
      float v = fmaxf(fmaxf(sc[0][r], sc[1][r]), fmaxf(sc[2][r], sc[3][r]));
      v = fmaxf(v, __shfl_xor(v, 1));
      v = fmaxf(v, __shfl_xor(v, 2));
      v = fmaxf(v, __shfl_xor(v, 4));
      v = fmaxf(v, __shfl_xor(v, 8));
      mnew[r] = fmaxf(mrun[r], v);
      corr[r] = __expf(mrun[r] - mnew[r]);
      mrun[r] = mnew[r];
      rs[r] = 0.f;
    }
#pragma unroll
    for (int t = 0; t < 4; ++t)
#pragma unroll
      for (int r = 0; r < 4; ++r) {
        float p = __expf(sc[t][r] - mnew[r]);
        sc[t][r] = p;
        rs[r] += p;
      }
#pragma unroll
    for (int r = 0; r < 4; ++r) {
      float s = rs[r];
      s += __shfl_xor(s, 1);
      s += __shfl_xor(s, 2);
      s += __shfl_xor(s, 4);
      s += __shfl_xor(s, 8);
      lrun[r] = lrun[r] * corr[r] + s;
#pragma unroll
      for (int t = 0; t < 4; ++t) acc[t][r] *= corr[r];
    }
    // P -> bf16 in LDS (wave-private strip)
#pragma unroll
    for (int t = 0; t < 4; ++t)
#pragma unroll
      for (int r = 0; r < 4; ++r)
        Pw[(4 * g + r) * 72 + t * 16 + l15] = f2bf(sc[t][r]);
    __syncthreads();   // conservative; also keeps waves in lockstep before PV

    // acc += P * V  (A = P rows, B = V via Vt)
#pragma unroll
    for (int ks = 0; ks < 2; ++ks) {
      frag16 pa = *reinterpret_cast<const frag16*>(&Pw[l15 * 72 + ks * 32 + 8 * g]);
#pragma unroll
      for (int t = 0; t < 4; ++t) {
        frag16 vb = *reinterpret_cast<const frag16*>(&Vt[(t * 16 + l15) * 72 + ks * 32 + 8 * g]);
        acc[t] = __builtin_amdgcn_mfma_f32_16x16x32_bf16(pa, vb, acc[t], 0, 0, 0);
      }
    }
  }

  // epilogue: ctx[b*N+q][h*64+d], normalized
  const int b = bh / HH, h = bh - b * HH;
#pragma unroll
  for (int r = 0; r < 4; ++r) {
    int qn = q0 + w * 16 + 4 * g + r;
    float inv = 1.0f / lrun[r];
#pragma unroll
    for (int t = 0; t < 4; ++t) {
      int d = t * 16 + l15;
      ctx[((size_t)(b * NN + qn)) * CC + h * DD + d] = f2bf(acc[t][r] * inv);
    }
  }
}

// ------------------------------------------------------------------------------
extern "C" void kernel_launch(void* const* d_in, const int* in_sizes, int n_in,
                              void* d_out, int out_size, void* d_ws, size_t ws_size,
                              hipStream_t stream) {
  const void* x = d_in[0];
  const void* qw = d_in[1];
  const void* pw = d_in[2];
  char* ws = (char*)d_ws;
  int* flag = (int*)ws;
  size_t off = 256;
  unsigned short* xb = (unsigned short*)(ws + off); off += (size_t)MTOT * CC * 2;   // reused as ctx
  unsigned short* qwb = (unsigned short*)(ws + off); off += (size_t)3 * CC * CC * 2;
  unsigned short* pwb = (unsigned short*)(ws + off); off += (size_t)CC * CC * 2;
  unsigned short* qkvbuf = (unsigned short*)(ws + off); off += (size_t)3 * MTOT * CC * 2;
  unsigned short* ctx = xb;  // x is consumed by QKV GEMM before attention writes ctx

  detect_k<<<1, 256, 0, stream>>>((const unsigned short*)x, flag);
  conv_k<<<1024, 256, 0, stream>>>(x, xb, MTOT * CC, flag);
  conv_k<<<512, 256, 0, stream>>>(qw, qwb, 3 * CC * CC, flag);
  conv_k<<<256, 256, 0, stream>>>(pw, pwb, CC * CC, flag);
  gemm_bt<0><<<dim3(MTOT / 128, (3 * CC) / 128), 256, 0, stream>>>(xb, qwb, qkvbuf, nullptr, flag);
  attn_k<<<dim3(NN / 64, BB * HH), 256, 0, stream>>>(qkvbuf, ctx);
  gemm_bt<1><<<dim3(MTOT / 128, CC / 128), 256, 0, stream>>>(ctx, pwb, nullptr, d_out, flag);
}